// Round 7
// baseline (110.804 us; speedup 1.0000x reference)
//
#include <hip/hip_runtime.h>

#define SS 14
#define NBOX 2
#define CCH 30                           // 5*NBOX + 20 classes
#define TILE_CELLS 32                    // cells per wave-tile
#define TILE_FLOATS (TILE_CELLS * CCH)   // 960 floats = 3840 bytes
#define WAVES_PER_BLOCK 4                // 256-thread blocks

typedef __attribute__((address_space(1))) const void as1_void;
typedef __attribute__((address_space(3))) void as3_void;

// Coalesced global->LDS DMA of one 3840-byte tile (32 cells x 120 B).
// HW-verified widths only: 3 x (64 lanes x 16B) + 3 x (64 lanes x 4B).
__device__ __forceinline__ void stage_tile(const float* __restrict__ g,
                                           float* l, int lane) {
    const char* gc = (const char*)g;
    char* lc = (char*)l;
#pragma unroll
    for (int j = 0; j < 3; ++j)
        __builtin_amdgcn_global_load_lds((as1_void*)(gc + j * 1024 + lane * 16),
                                         (as3_void*)(lc + j * 1024), 16, 0, 0);
#pragma unroll
    for (int j = 0; j < 3; ++j)
        __builtin_amdgcn_global_load_lds((as1_void*)(gc + 3072 + j * 256 + lane * 4),
                                         (as3_void*)(lc + 3072 + j * 256), 4, 0, 0);
}

// Per-cell YOLOv1 loss (identical math to the absmax-0.0 Round-1 kernel).
__device__ __forceinline__ float cell_loss(const float* p, const float* t) {
    float iou0 = 0.f, iou1 = 0.f, loc0 = 0.f, loc1 = 0.f;
#pragma unroll
    for (int b = 0; b < NBOX; ++b) {
        const int o = 5 * b;
        float thw = 0.5f * t[o + 2] * t[o + 2];
        float thh = 0.5f * t[o + 3] * t[o + 3];
        float phw = 0.5f * p[o + 2] * p[o + 2];
        float phh = 0.5f * p[o + 3] * p[o + 3];
        float t0x = t[o + 0] - thw, t0y = t[o + 1] - thh;
        float t1x = t[o + 0] + thw, t1y = t[o + 1] + thh;
        float p0x = p[o + 0] - phw, p0y = p[o + 1] - phh;
        float p1x = p[o + 0] + phw, p1y = p[o + 1] + phh;

        float ltx = fmaxf(t0x, p0x), lty = fmaxf(t0y, p0y);
        float rbx = fminf(t1x, p1x), rby = fminf(t1y, p1y);
        float w = fmaxf(rbx - ltx, 0.0f);
        float h = fmaxf(rby - lty, 0.0f);
        float inter = w * h;
        float a1 = (t1x - t0x) * (t1y - t0y);
        float a2 = (p1x - p0x) * (p1y - p0y);
        float denom = a1 + a2 - inter;
        float iou_b = (denom > 0.0f) ? (inter / denom) : 0.0f;

        float l = 0.0f;
#pragma unroll
        for (int k = 0; k < 4; ++k) {
            float d = p[o + k] - t[o + k];
            l += d * d;
        }
        if (b == 0) { iou0 = iou_b; loc0 = l; }
        else        { iou1 = iou_b; loc1 = l; }
    }

    int sel1 = (iou1 > iou0);               // argmax: first max on ties
    float max_iou = fmaxf(iou0, iou1);
    float loc   = sel1 ? loc1 : loc0;
    float pconf = sel1 ? p[9] : p[4];
    float tconf = sel1 ? t[9] : t[4];

    float cls = 0.0f;
#pragma unroll
    for (int k = 5 * NBOX; k < CCH; ++k) {
        float d = p[k] - t[k];
        cls += d * d;
    }

    float dcon = pconf - max_iou;
    float d4 = p[4] - t[4];
    float d9 = p[9] - t[9];
    float noobj = d4 * d4 + d9 * d9;
    float diou = max_iou - tconf;

    float objf = (t[4] > 0.0f) ? 1.0f : 0.0f;
    return objf * (5.0f * loc + cls + dcon * dcon + diou * diou)
         + (1.0f - objf) * 0.5f * noobj;
}

// Force <=64 VGPR (8 waves/SIMD allocator budget); LDS then caps occupancy
// at 5 blocks/CU = 20 waves/CU (62%). R1's compute fit in 40 VGPR.
__global__ __launch_bounds__(256, 8) void yolov1_loss_kernel(
    const float* __restrict__ pred, const float* __restrict__ target,
    float* __restrict__ out, int ncells, float inv_batch)
{
    // Single buffer pair per wave: 4 waves x 7680 B = 30720 B/block.
    // Each wave owns its chunk -> no __syncthreads anywhere.
    __shared__ __align__(16) float lds[WAVES_PER_BLOCK * 2 * TILE_FLOATS];

    const int lane = threadIdx.x & 63;
    const int wid  = threadIdx.x >> 6;
    const int w    = blockIdx.x * WAVES_PER_BLOCK + wid;
    const int W    = gridDim.x * WAVES_PER_BLOCK;
    const int ntiles = ncells / TILE_CELLS;

    float* myp = lds + wid * (2 * TILE_FLOATS);
    float* myt = myp + TILE_FLOATS;

    float acc = 0.0f;
    int tile = w;
    if (tile < ntiles) {
        stage_tile(pred   + (size_t)tile * TILE_FLOATS, myp, lane);
        stage_tile(target + (size_t)tile * TILE_FLOATS, myt, lane);
        for (;;) {
            const int next = tile + W;
            // DMA for current tile complete before ds_reads
            asm volatile("s_waitcnt vmcnt(0)" ::: "memory");
            __builtin_amdgcn_sched_barrier(0);

            float p[CCH], t[CCH];
            if (lane < TILE_CELLS) {
                const float2* pl = (const float2*)(myp + lane * CCH);
                const float2* tl = (const float2*)(myt + lane * CCH);
#pragma unroll
                for (int k = 0; k < CCH / 2; ++k) {
                    float2 a = pl[k]; p[2 * k] = a.x; p[2 * k + 1] = a.y;
                    float2 b = tl[k]; t[2 * k] = b.x; t[2 * k + 1] = b.y;
                }
            }
            // drain ds_reads before DMA may overwrite the buffer (WAR)
            asm volatile("s_waitcnt lgkmcnt(0)" ::: "memory");
            __builtin_amdgcn_sched_barrier(0);

            if (next < ntiles) {   // depth-1 prefetch overlaps compute
                stage_tile(pred   + (size_t)next * TILE_FLOATS, myp, lane);
                stage_tile(target + (size_t)next * TILE_FLOATS, myt, lane);
            }
            if (lane < TILE_CELLS)
                acc += cell_loss(p, t);
            if (next >= ntiles) break;
            tile = next;
        }
    }

    // remainder cells (ncells % 32 != 0) — zero iterations for this shape
    for (int cell = ntiles * TILE_CELLS + w * 64 + lane; cell < ncells;
         cell += W * 64) {
        float p[CCH], t[CCH];
        const float2* pp = (const float2*)(pred + (size_t)cell * CCH);
        const float2* tp = (const float2*)(target + (size_t)cell * CCH);
#pragma unroll
        for (int k = 0; k < CCH / 2; ++k) {
            float2 a = pp[k]; p[2 * k] = a.x; p[2 * k + 1] = a.y;
            float2 b = tp[k]; t[2 * k] = b.x; t[2 * k + 1] = b.y;
        }
        acc += cell_loss(p, t);
    }

    // wave(64) shuffle reduction, one atomic per wave
#pragma unroll
    for (int off = 32; off > 0; off >>= 1)
        acc += __shfl_down(acc, off, 64);
    if (lane == 0)
        atomicAdd(out, acc * inv_batch);
}

extern "C" void kernel_launch(void* const* d_in, const int* in_sizes, int n_in,
                              void* d_out, int out_size, void* d_ws, size_t ws_size,
                              hipStream_t stream) {
    const float* pred = (const float*)d_in[0];
    const float* target = (const float*)d_in[1];
    float* out = (float*)d_out;

    int ncells = in_sizes[0] / CCH;           // batch * S * S = 1,605,632
    int batch = ncells / (SS * SS);           // 8192
    float inv_batch = 1.0f / (float)batch;

    hipMemsetAsync(d_out, 0, sizeof(float) * out_size, stream);

    const int threads = 256;                   // 4 waves/block
    int blocks = 1280;                         // 5 blocks/CU -> 20 waves/CU
    yolov1_loss_kernel<<<blocks, threads, 0, stream>>>(pred, target, out,
                                                       ncells, inv_batch);
}

// Round 8
// 83.517 us; speedup vs baseline: 1.3267x; 1.3267x over previous
//
#include <hip/hip_runtime.h>

#define SS 14
#define NBOX 2
#define CCH 30   // 5*NBOX + 20 classes

// Full per-cell loss for OBJ cells only (objf==1):
// 5*loc + cls + containment + iou terms. Identical math to the verified
// (absmax 0.0) Round-1 kernel's obj path.
__device__ __forceinline__ float obj_loss(const float* p, const float* t) {
    float iou0 = 0.f, iou1 = 0.f, loc0 = 0.f, loc1 = 0.f;
#pragma unroll
    for (int b = 0; b < NBOX; ++b) {
        const int o = 5 * b;
        float thw = 0.5f * t[o + 2] * t[o + 2];
        float thh = 0.5f * t[o + 3] * t[o + 3];
        float phw = 0.5f * p[o + 2] * p[o + 2];
        float phh = 0.5f * p[o + 3] * p[o + 3];
        float t0x = t[o + 0] - thw, t0y = t[o + 1] - thh;
        float t1x = t[o + 0] + thw, t1y = t[o + 1] + thh;
        float p0x = p[o + 0] - phw, p0y = p[o + 1] - phh;
        float p1x = p[o + 0] + phw, p1y = p[o + 1] + phh;

        float ltx = fmaxf(t0x, p0x), lty = fmaxf(t0y, p0y);
        float rbx = fminf(t1x, p1x), rby = fminf(t1y, p1y);
        float w = fmaxf(rbx - ltx, 0.0f);
        float h = fmaxf(rby - lty, 0.0f);
        float inter = w * h;
        float a1 = (t1x - t0x) * (t1y - t0y);
        float a2 = (p1x - p0x) * (p1y - p0y);
        float denom = a1 + a2 - inter;
        float iou_b = (denom > 0.0f) ? (inter / denom) : 0.0f;

        float l = 0.0f;
#pragma unroll
        for (int k = 0; k < 4; ++k) {
            float d = p[o + k] - t[o + k];
            l += d * d;
        }
        if (b == 0) { iou0 = iou_b; loc0 = l; }
        else        { iou1 = iou_b; loc1 = l; }
    }

    int sel1 = (iou1 > iou0);               // argmax: first max on ties
    float max_iou = fmaxf(iou0, iou1);
    float loc   = sel1 ? loc1 : loc0;
    float pconf = sel1 ? p[9] : p[4];
    float tconf = sel1 ? t[9] : t[4];

    float cls = 0.0f;
#pragma unroll
    for (int k = 5 * NBOX; k < CCH; ++k) {
        float d = p[k] - t[k];
        cls += d * d;
    }

    float dcon = pconf - max_iou;
    float diou = max_iou - tconf;
    return 5.0f * loc + cls + dcon * dcon + diou * diou;
}

// Sparse read: every lane loads only the 4 conf dwords; the ~10% obj lanes
// additionally load their full 120B cells under the exec mask.
__global__ __launch_bounds__(256) void yolov1_loss_kernel(
    const float* __restrict__ pred, const float* __restrict__ target,
    float* __restrict__ out, int ncells, float inv_batch)
{
    float acc = 0.0f;
    int tid = blockIdx.x * blockDim.x + threadIdx.x;
    int stride = gridDim.x * blockDim.x;

    for (int cell = tid; cell < ncells; cell += stride) {
        const float* pc = pred + (size_t)cell * CCH;
        const float* tc = target + (size_t)cell * CCH;

        float t4 = tc[4];
        float t9 = tc[9];
        float p4 = pc[4];
        float p9 = pc[9];

        if (t4 > 0.0f) {
            // obj cell (~10%): full 120B load of both cells, exec-masked
            float p[CCH], t[CCH];
            const float2* pl = reinterpret_cast<const float2*>(pc);
            const float2* tl = reinterpret_cast<const float2*>(tc);
#pragma unroll
            for (int k = 0; k < CCH / 2; ++k) {
                float2 a = pl[k]; p[2 * k] = a.x; p[2 * k + 1] = a.y;
                float2 b = tl[k]; t[2 * k] = b.x; t[2 * k + 1] = b.y;
            }
            acc += obj_loss(p, t);
        } else {
            // noobj cell: conf MSE of both boxes only
            float d4 = p4 - t4;
            float d9 = p9 - t9;
            acc += 0.5f * (d4 * d4 + d9 * d9);
        }
    }

    // wave(64) shuffle reduction
#pragma unroll
    for (int off = 32; off > 0; off >>= 1)
        acc += __shfl_down(acc, off, 64);

    __shared__ float wsum[4];
    int lane = threadIdx.x & 63;
    int wid = threadIdx.x >> 6;
    if (lane == 0) wsum[wid] = acc;
    __syncthreads();
    if (threadIdx.x == 0) {
        float s = wsum[0] + wsum[1] + wsum[2] + wsum[3];
        atomicAdd(out, s * inv_batch);
    }
}

extern "C" void kernel_launch(void* const* d_in, const int* in_sizes, int n_in,
                              void* d_out, int out_size, void* d_ws, size_t ws_size,
                              hipStream_t stream) {
    const float* pred = (const float*)d_in[0];
    const float* target = (const float*)d_in[1];
    float* out = (float*)d_out;

    int ncells = in_sizes[0] / CCH;           // batch * S * S = 1,605,632
    int batch = ncells / (SS * SS);           // 8192
    float inv_batch = 1.0f / (float)batch;    // exact

    hipMemsetAsync(d_out, 0, sizeof(float) * out_size, stream);

    const int threads = 256;
    int blocks = (ncells + threads - 1) / threads;
    if (blocks > 2048) blocks = 2048;
    yolov1_loss_kernel<<<blocks, threads, 0, stream>>>(pred, target, out,
                                                       ncells, inv_batch);
}

// Round 9
// 77.630 us; speedup vs baseline: 1.4273x; 1.0758x over previous
//
#include <hip/hip_runtime.h>

#define SS 14
#define NBOX 2
#define CCH 30                         // 5*NBOX + 20 classes
#define TILE_CELLS 64                  // cells per wave-tile
#define TILE_FLOATS (TILE_CELLS * CCH) // 1920 floats = 7680 bytes
#define WAVES_PER_BLOCK 2              // 128-thread blocks
#define OPS_PER_TILE 18                // 2 tensors x (7x16B + 2x4B) DMA ops

typedef __attribute__((address_space(1))) const void as1_void;
typedef __attribute__((address_space(3))) void as3_void;

// Coalesced global->LDS DMA of one 7680-byte tile (64 cells x 120 B).
// HW-verified widths only: 7 x (64 lanes x 16B) + 2 x (64 lanes x 4B).
__device__ __forceinline__ void stage_tile(const float* __restrict__ g,
                                           float* l, int lane) {
    const char* gc = (const char*)g;
    char* lc = (char*)l;
#pragma unroll
    for (int j = 0; j < 7; ++j)
        __builtin_amdgcn_global_load_lds((as1_void*)(gc + j * 1024 + lane * 16),
                                         (as3_void*)(lc + j * 1024), 16, 0, 0);
#pragma unroll
    for (int j = 0; j < 2; ++j)
        __builtin_amdgcn_global_load_lds((as1_void*)(gc + 7168 + j * 256 + lane * 4),
                                         (as3_void*)(lc + 7168 + j * 256), 4, 0, 0);
}

// Per-cell YOLOv1 loss (identical math to the absmax-0.0 Round-1 kernel).
__device__ __forceinline__ float cell_loss(const float* p, const float* t) {
    float iou0 = 0.f, iou1 = 0.f, loc0 = 0.f, loc1 = 0.f;
#pragma unroll
    for (int b = 0; b < NBOX; ++b) {
        const int o = 5 * b;
        float thw = 0.5f * t[o + 2] * t[o + 2];
        float thh = 0.5f * t[o + 3] * t[o + 3];
        float phw = 0.5f * p[o + 2] * p[o + 2];
        float phh = 0.5f * p[o + 3] * p[o + 3];
        float t0x = t[o + 0] - thw, t0y = t[o + 1] - thh;
        float t1x = t[o + 0] + thw, t1y = t[o + 1] + thh;
        float p0x = p[o + 0] - phw, p0y = p[o + 1] - phh;
        float p1x = p[o + 0] + phw, p1y = p[o + 1] + phh;

        float ltx = fmaxf(t0x, p0x), lty = fmaxf(t0y, p0y);
        float rbx = fminf(t1x, p1x), rby = fminf(t1y, p1y);
        float w = fmaxf(rbx - ltx, 0.0f);
        float h = fmaxf(rby - lty, 0.0f);
        float inter = w * h;
        float a1 = (t1x - t0x) * (t1y - t0y);
        float a2 = (p1x - p0x) * (p1y - p0y);
        float denom = a1 + a2 - inter;
        float iou_b = (denom > 0.0f) ? (inter / denom) : 0.0f;

        float l = 0.0f;
#pragma unroll
        for (int k = 0; k < 4; ++k) {
            float d = p[o + k] - t[o + k];
            l += d * d;
        }
        if (b == 0) { iou0 = iou_b; loc0 = l; }
        else        { iou1 = iou_b; loc1 = l; }
    }

    int sel1 = (iou1 > iou0);               // argmax: first max on ties
    float max_iou = fmaxf(iou0, iou1);
    float loc   = sel1 ? loc1 : loc0;
    float pconf = sel1 ? p[9] : p[4];
    float tconf = sel1 ? t[9] : t[4];

    float cls = 0.0f;
#pragma unroll
    for (int k = 5 * NBOX; k < CCH; ++k) {
        float d = p[k] - t[k];
        cls += d * d;
    }

    float dcon = pconf - max_iou;
    float d4 = p[4] - t[4];
    float d9 = p[9] - t[9];
    float noobj = d4 * d4 + d9 * d9;
    float diou = max_iou - tconf;

    float objf = (t[4] > 0.0f) ? 1.0f : 0.0f;
    return objf * (5.0f * loc + cls + dcon * dcon + diou * diou)
         + (1.0f - objf) * 0.5f * noobj;
}

__global__ __launch_bounds__(128) void yolov1_loss_kernel(
    const float* __restrict__ pred, const float* __restrict__ target,
    float* __restrict__ out, int ncells, float inv_batch)
{
    // 2 waves x 2 buffers x (pred+target tile) = 61440 B; each wave owns its
    // chunk -> no __syncthreads anywhere.
    __shared__ __align__(16) float lds[WAVES_PER_BLOCK * 4 * TILE_FLOATS];

    const int lane = threadIdx.x & 63;
    const int wid  = threadIdx.x >> 6;
    const int w    = blockIdx.x * WAVES_PER_BLOCK + wid;
    const int W    = gridDim.x * WAVES_PER_BLOCK;
    const int ntiles = ncells / TILE_CELLS;

    float* base = lds + wid * (4 * TILE_FLOATS);
    float* curp = base;
    float* curt = base + TILE_FLOATS;
    float* nxtp = base + 2 * TILE_FLOATS;
    float* nxtt = base + 3 * TILE_FLOATS;

    float acc = 0.0f;
    int t_cur = w;
    if (t_cur < ntiles) {
        // prologue: stage depth-2
        stage_tile(pred   + (size_t)t_cur * TILE_FLOATS, curp, lane);
        stage_tile(target + (size_t)t_cur * TILE_FLOATS, curt, lane);
        if (t_cur + W < ntiles) {
            stage_tile(pred   + (size_t)(t_cur + W) * TILE_FLOATS, nxtp, lane);
            stage_tile(target + (size_t)(t_cur + W) * TILE_FLOATS, nxtt, lane);
        }
        for (;;) {
            const int t_pre = t_cur + 2 * W;
            // counted wait: current tile's 18 DMA done, next tile's 18 may fly
            if (t_cur + W < ntiles)
                asm volatile("s_waitcnt vmcnt(18)" ::: "memory");
            else
                asm volatile("s_waitcnt vmcnt(0)" ::: "memory");
            __builtin_amdgcn_sched_barrier(0);

            float p[CCH], t[CCH];
            const float2* pl = (const float2*)(curp + lane * CCH);
            const float2* tl = (const float2*)(curt + lane * CCH);
#pragma unroll
            for (int k = 0; k < CCH / 2; ++k) {
                float2 a = pl[k]; p[2 * k] = a.x; p[2 * k + 1] = a.y;
                float2 b = tl[k]; t[2 * k] = b.x; t[2 * k + 1] = b.y;
            }
            // drain ds_reads before DMA may overwrite this buffer (WAR)
            asm volatile("s_waitcnt lgkmcnt(0)" ::: "memory");
            __builtin_amdgcn_sched_barrier(0);

            if (t_pre < ntiles) {   // re-stage just-read buffer with t+2W
                stage_tile(pred   + (size_t)t_pre * TILE_FLOATS, curp, lane);
                stage_tile(target + (size_t)t_pre * TILE_FLOATS, curt, lane);
            }
            acc += cell_loss(p, t);

            t_cur += W;
            if (t_cur >= ntiles) break;
            float* s;
            s = curp; curp = nxtp; nxtp = s;
            s = curt; curt = nxtt; nxtt = s;
        }
    }

    // remainder cells (ncells % 64 != 0) — zero iterations for this shape
    for (int cell = ntiles * TILE_CELLS + w * 64 + lane; cell < ncells;
         cell += W * 64) {
        float p[CCH], t[CCH];
        const float2* pp = (const float2*)(pred + (size_t)cell * CCH);
        const float2* tp = (const float2*)(target + (size_t)cell * CCH);
#pragma unroll
        for (int k = 0; k < CCH / 2; ++k) {
            float2 a = pp[k]; p[2 * k] = a.x; p[2 * k + 1] = a.y;
            float2 b = tp[k]; t[2 * k] = b.x; t[2 * k + 1] = b.y;
        }
        acc += cell_loss(p, t);
    }

    // wave(64) shuffle reduction, one atomic per wave
#pragma unroll
    for (int off = 32; off > 0; off >>= 1)
        acc += __shfl_down(acc, off, 64);
    if (lane == 0)
        atomicAdd(out, acc * inv_batch);
}

extern "C" void kernel_launch(void* const* d_in, const int* in_sizes, int n_in,
                              void* d_out, int out_size, void* d_ws, size_t ws_size,
                              hipStream_t stream) {
    const float* pred = (const float*)d_in[0];
    const float* target = (const float*)d_in[1];
    float* out = (float*)d_out;

    int ncells = in_sizes[0] / CCH;           // batch * S * S = 1,605,632
    int batch = ncells / (SS * SS);           // 8192
    float inv_batch = 1.0f / (float)batch;

    hipMemsetAsync(d_out, 0, sizeof(float) * out_size, stream);

    const int threads = 128;                   // 2 waves/block
    int blocks = 512;                          // 2 blocks/CU (LDS-capped), all resident
    yolov1_loss_kernel<<<blocks, threads, 0, stream>>>(pred, target, out,
                                                       ncells, inv_batch);
}